// Round 12
// baseline (154.982 us; speedup 1.0000x reference)
//
#include <hip/hip_runtime.h>

#define HH 512
#define WW 1024
#define NC 19
#define HWP (HH * WW)
#define NB 4
#define NREP 4
#define NXCD 8
#define IGNORE_IDX 255

typedef float f2v __attribute__((ext_vector_type(2)));
typedef float f4v __attribute__((ext_vector_type(4)));
typedef int   i4v __attribute__((ext_vector_type(4)));

// R4 structure with WIDE coalesced loads: 4 px/thread, targets f4v (19 instr
// per 4 px instead of 19 per px), flow 2xf4v, labels i4v. Gathers stay
// scalar (channel-major layout makes them irreducible) and the exp stays in
// the compiler's rolling window (R10 showed explicit hoisting hurts).
// ws layout: float acc[NREP][NB][NC][2]
__global__ __launch_bounds__(256) void tc_main(
    const float* __restrict__ preds,
    const float* __restrict__ targets,
    const float* __restrict__ flow,
    const int* __restrict__ labels,
    float* __restrict__ acc)
{
    const int tid = threadIdx.x;

    // XCD-chunked swizzle (R4 win)
    const int nwg   = gridDim.x;            // 2048
    const int chunk = nwg / NXCD;           // 256
    const int phys  = blockIdx.x;
    const int logical = (phys % NXCD) * chunk + phys / NXCD;

    const int blocks_per_img = nwg / NB;    // 512
    const int b   = logical / blocks_per_img;
    const int blk = logical % blocks_per_img;

    const float* tb = targets + (size_t)b * NC * HWP;
    const float* pb = preds   + (size_t)b * NC * HWP;
    const float* fb = flow    + (size_t)b * HWP * 2;
    const int*   lb = labels  + (size_t)b * HWP;

    const int base = blk * 1024;            // one image row
    const int y    = base >> 10;

    float accn[NC], accd[NC];
#pragma unroll
    for (int c = 0; c < NC; ++c) { accn[c] = 0.f; accd[c] = 0.f; }

    // ---- this thread's 4 consecutive pixels ----
    const int x0  = 4 * tid;
    const int pix = base + x0;

    const f4v fA = __builtin_nontemporal_load((const f4v*)(fb + (size_t)pix * 2));
    const f4v fB = __builtin_nontemporal_load((const f4v*)(fb + (size_t)pix * 2 + 4));
    const i4v lab = __builtin_nontemporal_load((const i4v*)(lb + pix));

    int   sp[4];
    float vf[4];
    {
        const float dx[4] = {fA.x, fA.z, fB.x, fB.z};
        const float dy[4] = {fA.y, fA.w, fB.y, fB.w};
#pragma unroll
        for (int j = 0; j < 4; ++j) {
            const int rx = (int)rintf((float)(x0 + j) + dx[j]);  // half-even
            const int ry = (int)rintf((float)y + dy[j]);
            const bool valid = (rx >= 0) && (rx < WW) && (ry >= 0) && (ry < HH);
            sp[j] = min(max(ry, 0), HH - 1) * WW + min(max(rx, 0), WW - 1);
            vf[j] = valid ? 1.f : 0.f;
        }
    }

    const float keep[4] = {
        (lab.x != IGNORE_IDX) ? 1.f : 0.f,
        (lab.y != IGNORE_IDX) ? 1.f : 0.f,
        (lab.z != IGNORE_IDX) ? 1.f : 0.f,
        (lab.w != IGNORE_IDX) ? 1.f : 0.f };

    // ---- rolling per-channel loop: 1 f4v target load + 4 gathers ----
    float te[NC][4], pe[NC][4];
    float tsum[4] = {0.f, 0.f, 0.f, 0.f};
    float psum[4] = {0.f, 0.f, 0.f, 0.f};
#pragma unroll
    for (int c = 0; c < NC; ++c) {
        const float* pc = pb + (size_t)c * HWP;
        const f4v tv = __builtin_nontemporal_load(
            (const f4v*)(tb + (size_t)c * HWP + pix));
        const float g0 = pc[sp[0]];
        const float g1 = pc[sp[1]];
        const float g2 = pc[sp[2]];
        const float g3 = pc[sp[3]];

        te[c][0] = __expf(tv.x); tsum[0] += te[c][0];
        te[c][1] = __expf(tv.y); tsum[1] += te[c][1];
        te[c][2] = __expf(tv.z); tsum[2] += te[c][2];
        te[c][3] = __expf(tv.w); tsum[3] += te[c][3];
        pe[c][0] = __expf(g0);   psum[0] += pe[c][0];
        pe[c][1] = __expf(g1);   psum[1] += pe[c][1];
        pe[c][2] = __expf(g2);   psum[2] += pe[c][2];
        pe[c][3] = __expf(g3);   psum[3] += pe[c][3];
    }

    float ti[4], pi[4];
#pragma unroll
    for (int j = 0; j < 4; ++j) {
        ti[j] = keep[j] / tsum[j];
        pi[j] = vf[j] / psum[j];
    }

#pragma unroll
    for (int c = 0; c < NC; ++c) {
        float n = 0.f, d = 0.f;
#pragma unroll
        for (int j = 0; j < 4; ++j) {
            const float t = te[c][j] * ti[j];
            const float p = pe[c][j] * pi[j];
            const float pt = p * t;
            n += pt;
            d += p + t - pt;
        }
        accn[c] += n;
        accd[c] += d;
    }

    // ---- reduction: wave shuffle -> LDS -> one atomic per value ----
#pragma unroll
    for (int c = 0; c < NC; ++c) {
        for (int off = 32; off > 0; off >>= 1) {
            accn[c] += __shfl_xor(accn[c], off);
            accd[c] += __shfl_xor(accd[c], off);
        }
    }

    __shared__ float s[4][NC][2];
    const int wave = tid >> 6;
    const int lane = tid & 63;
    if (lane == 0) {
#pragma unroll
        for (int c = 0; c < NC; ++c) {
            s[wave][c][0] = accn[c];
            s[wave][c][1] = accd[c];
        }
    }
    __syncthreads();
    if (tid < NC * 2) {
        const int c = tid >> 1;
        const int which = tid & 1;
        const float v = s[0][c][which] + s[1][c][which] + s[2][c][which] + s[3][c][which];
        const int rep = phys & (NREP - 1);
        atomicAdd(&acc[(((size_t)rep * NB + b) * NC + c) * 2 + which], v);
    }
}

__global__ void tc_final(const float* __restrict__ acc, float* __restrict__ out)
{
    if (threadIdx.x == 0 && blockIdx.x == 0) {
        float total = 0.f;
        for (int b = 0; b < NB; ++b) {
            float m = 0.f;
            for (int c = 0; c < NC; ++c) {
                float n = 0.f, d = 0.f;
                for (int r = 0; r < NREP; ++r) {
                    n += acc[(((size_t)r * NB + b) * NC + c) * 2 + 0];
                    d += acc[(((size_t)r * NB + b) * NC + c) * 2 + 1];
                }
                m += n / d;
            }
            total += 1.0f - m / (float)NC;
        }
        out[0] = total / (float)NB;
    }
}

extern "C" void kernel_launch(void* const* d_in, const int* in_sizes, int n_in,
                              void* d_out, int out_size, void* d_ws, size_t ws_size,
                              hipStream_t stream) {
    const float* preds   = (const float*)d_in[0];
    const float* targets = (const float*)d_in[1];
    const float* flow    = (const float*)d_in[2];
    const int*   labels  = (const int*)d_in[3];
    float* acc = (float*)d_ws;

    (void)hipMemsetAsync(acc, 0, (size_t)NREP * NB * NC * 2 * sizeof(float), stream);

    tc_main<<<2048, 256, 0, stream>>>(preds, targets, flow, labels, acc);
    tc_final<<<1, 64, 0, stream>>>(acc, (float*)d_out);
}